// Round 8
// baseline (329.586 us; speedup 1.0000x reference)
//
#include <hip/hip_runtime.h>

typedef __attribute__((ext_vector_type(8))) short short8;
typedef __attribute__((ext_vector_type(4))) float float4v;

__device__ __forceinline__ unsigned short f2bf(float f) {
  unsigned int u = __float_as_uint(f);
  u += 0x7fffu + ((u >> 16) & 1u);   // round-to-nearest-even
  return (unsigned short)(u >> 16);
}
__device__ __forceinline__ float bf2f(unsigned short h) {
  return __uint_as_float(((unsigned int)h) << 16);
}
__device__ __forceinline__ unsigned int pack2bf(float a, float b) {
  return (unsigned int)f2bf(a) | ((unsigned int)f2bf(b) << 16);
}

// ---- prep: w' = gamma*w -> bf16 in MFMA FRAGMENT ORDER + colsum + bias ------
// w_frag[((ntile*24 + kc)*64 + lq*16 + lrow)*8 + e]; n = ntile*16+lrow,
// k' = kc*32 + lq*8 + e; k_orig = (k'&7)*96 + (k'>>3).
__global__ __launch_bounds__(256)
void prep_kernel(const float* __restrict__ w_red, const float* __restrict__ gamma,
                 const float* __restrict__ beta, unsigned short* __restrict__ w_frag,
                 float* __restrict__ colsum, float* __restrict__ bias) {
  const int n = blockIdx.x;       // 0..191
  const int t = threadIdx.x;      // 0..255
  const int ntile = n >> 4, lrow = n & 15;
  float cs = 0.f, bs = 0.f;
#pragma unroll
  for (int j = 0; j < 3; ++j) {
    int kp = j * 256 + t;                       // k' 0..767
    int ko = (kp & 7) * 96 + (kp >> 3);         // original k
    float w = w_red[(size_t)ko * 192 + n];
    unsigned short v = f2bf(gamma[ko] * w);
    int kc = kp >> 5, r = kp & 31, lq = r >> 3, e = r & 7;
    w_frag[(size_t)((ntile * 24 + kc) * 64 + lq * 16 + lrow) * 8 + e] = v;
    cs += bf2f(v);
    bs += beta[ko] * w;
  }
#pragma unroll
  for (int off = 1; off < 64; off <<= 1) {
    cs += __shfl_xor(cs, off, 64);
    bs += __shfl_xor(bs, off, 64);
  }
  __shared__ float red[2][4];
  const int wave = t >> 6;
  if ((t & 63) == 0) { red[0][wave] = cs; red[1][wave] = bs; }
  __syncthreads();
  if (t == 0) {
    colsum[n] = red[0][0] + red[0][1] + red[0][2] + red[0][3];
    bias[n]   = red[1][0] + red[1][1] + red[1][2] + red[1][3];
  }
}

// ---- main: fused pipeline v2 — B-before-D issue order (in-order vmcnt), -----
// 4 F-slots (2-phase DMA hiding), occupancy 6 blocks/CU.
// Per phase it: barrier | LOADB(it+1) | DMA(it+3) | vmcnt(8) | PACK(it+1)
// | 6 MFMA(it). Steady queue after vmcnt: [D(it+2), B(it+1)x6, D(it+3)] = 8.
__global__ __launch_bounds__(256, 6)
void pm_kernel(const float* __restrict__ x, const unsigned short* __restrict__ w_frag,
               const float* __restrict__ colsum, const float* __restrict__ bias,
               float* __restrict__ out) {
  __shared__ __align__(16) float F[4096];            // 4 slots x 1024 f32 (16 KB)
  __shared__ __align__(16) unsigned short Yb[2048];  // 2 x 16px x 64k bf16 (4 KB)
  __shared__ float4 part4[4][8];
  __shared__ float smu[16], srs[16];

  const int tid = threadIdx.x;
  const int bid = blockIdx.x;
  const int b  = bid >> 10;
  const int dz = (bid >> 6) & 15;
  const int hy = (bid >> 1) & 31;
  const int wh = bid & 1;

  const float* xb = x + (size_t)b * 12582912u + (size_t)dz * 8192u
                      + (size_t)hy * 128u + wh * 32;
  const int r0 = tid >> 3;
  const int c0 = r0 >> 2;          // 0..7; chunk channel c = c0 + 8*it
  const int di = (r0 >> 1) & 1;
  const int hi = r0 & 1;
  const int w0 = (tid & 7) << 2;
  const float* xp = xb + (size_t)c0 * 131072u + di * 4096 + hi * 64 + w0;

  const int lane = tid & 63;
  const int wave = tid >> 6;
  const int lrow = lane & 15;
  const int lq   = lane >> 4;

  // LDS addressing (bytes). A-tile rows are 128 B -> XOR-swizzle (G4).
  char* ybase = (char*)Yb;
  const int wx0 = (tid & 7) << 1;                  // px row pair written by thread
  const int k00 = c0 * 8 + di * 4 + hi * 2;        // chunk-local k (const!)
  const int b0off = (wx0 * 128 + k00 * 2) ^ ((wx0 & 7) << 4);
  const int b1off = ((wx0 + 1) * 128 + k00 * 2) ^ (((wx0 + 1) & 7) << 4);
  const int ra0 = (lrow * 128 + lq * 16) ^ ((lrow & 7) << 4);        // ks=0
  const int ra1 = (lrow * 128 + 64 + lq * 16) ^ ((lrow & 7) << 4);   // ks=1
  const int fth = wave * 256 + lane * 4;   // thread's float4 in an F slot
  const int fwv = wave * 256;              // wave-uniform DMA dest in an F slot

  // B fragment pointers (fragment-order w_frag -> contiguous 1KB/wave loads).
  const unsigned short* wb0 = w_frag + (size_t)(wave * 3 + 0) * 12288u + lane * 8;
  const unsigned short* wb1 = w_frag + (size_t)(wave * 3 + 1) * 12288u + lane * 8;
  const unsigned short* wb2 = w_frag + (size_t)(wave * 3 + 2) * 12288u + lane * 8;

  short8 bA[6], bB[6];
  float4v acc[3];
#pragma unroll
  for (int j = 0; j < 3; ++j)
#pragma unroll
    for (int r = 0; r < 4; ++r) acc[j][r] = 0.f;
  float sum0 = 0.f, sq0 = 0.f, sum1 = 0.f, sq1 = 0.f;

#define DMA(IT, SL)                                                            \
  __builtin_amdgcn_global_load_lds(                                            \
      (const __attribute__((address_space(1))) unsigned int*)(xp + (size_t)(IT) * 1048576u), \
      (__attribute__((address_space(3))) unsigned int*)&F[(SL) * 1024 + fwv], 16, 0, 0)

#define LOADB(BN, ITB)                                                         \
  do {                                                                         \
    const unsigned short* kp0 = wb0 + (ITB) * 1024;                            \
    BN[0] = *(const short8*)(kp0);                                             \
    BN[1] = *(const short8*)(kp0 + 512);                                       \
    const unsigned short* kp1 = wb1 + (ITB) * 1024;                            \
    BN[2] = *(const short8*)(kp1);                                             \
    BN[3] = *(const short8*)(kp1 + 512);                                       \
    const unsigned short* kp2 = wb2 + (ITB) * 1024;                            \
    BN[4] = *(const short8*)(kp2);                                             \
    BN[5] = *(const short8*)(kp2 + 512);                                       \
  } while (0)

#define PACK(SLP, PN)                                                          \
  do {                                                                         \
    float4 vv = *(const float4*)&F[(SLP) * 1024 + fth];                        \
    *(unsigned int*)(ybase + (PN) * 2048 + b0off) = pack2bf(vv.x, vv.y);       \
    *(unsigned int*)(ybase + (PN) * 2048 + b1off) = pack2bf(vv.z, vv.w);       \
    sum0 += vv.x + vv.y;  sq0 += vv.x * vv.x + vv.y * vv.y;                    \
    sum1 += vv.z + vv.w;  sq1 += vv.z * vv.z + vv.w * vv.w;                    \
  } while (0)

#define PHASE(IT, PC, PN, BC, BN, SLI, SLP)                                    \
  do {                                                                         \
    asm volatile("s_waitcnt lgkmcnt(0)" ::: "memory");                         \
    __builtin_amdgcn_s_barrier();                                              \
    { int itb = (IT) + 1 <= 11 ? (IT) + 1 : 11; LOADB(BN, itb); }              \
    __builtin_amdgcn_sched_barrier(0);                                         \
    { int itn = (IT) + 3 <= 11 ? (IT) + 3 : 11; DMA(itn, SLI); }               \
    __builtin_amdgcn_sched_barrier(0);                                         \
    asm volatile("s_waitcnt vmcnt(8)" ::: "memory");                           \
    __builtin_amdgcn_sched_barrier(0);                                         \
    if ((IT) < 11) PACK(SLP, PN);                                              \
    { short8 a0 = *(const short8*)(ybase + (PC) * 2048 + ra0);                 \
      short8 a1 = *(const short8*)(ybase + (PC) * 2048 + ra1);                 \
      acc[0] = __builtin_amdgcn_mfma_f32_16x16x32_bf16(a0, BC[0], acc[0], 0, 0, 0); \
      acc[0] = __builtin_amdgcn_mfma_f32_16x16x32_bf16(a1, BC[1], acc[0], 0, 0, 0); \
      acc[1] = __builtin_amdgcn_mfma_f32_16x16x32_bf16(a0, BC[2], acc[1], 0, 0, 0); \
      acc[1] = __builtin_amdgcn_mfma_f32_16x16x32_bf16(a1, BC[3], acc[1], 0, 0, 0); \
      acc[2] = __builtin_amdgcn_mfma_f32_16x16x32_bf16(a0, BC[4], acc[2], 0, 0, 0); \
      acc[2] = __builtin_amdgcn_mfma_f32_16x16x32_bf16(a1, BC[5], acc[2], 0, 0, 0); } \
  } while (0)

  // Prologue. Issue order D0,D1,B0x6,D2 -> queue 9; vmcnt(8) retires D0 only.
  // Entering phase 0: [D1, B0x6, D2] = 8 outstanding (the loop invariant).
  DMA(0, 0);
  __builtin_amdgcn_sched_barrier(0);
  DMA(1, 1);
  __builtin_amdgcn_sched_barrier(0);
  LOADB(bA, 0);
  __builtin_amdgcn_sched_barrier(0);
  DMA(2, 2);
  __builtin_amdgcn_sched_barrier(0);
  asm volatile("s_waitcnt vmcnt(8)" ::: "memory");
  __builtin_amdgcn_sched_barrier(0);
  PACK(0, 0);   // chunk 0 -> Yb parity 0

  // 12 phases; pattern period 4 (slots mod 4, parity mod 2, bA/bB mod 2).
#pragma unroll
  for (int it4 = 0; it4 < 12; it4 += 4) {
    PHASE(it4 + 0, 0, 1, bA, bB, 3, 1);
    PHASE(it4 + 1, 1, 0, bB, bA, 0, 2);
    PHASE(it4 + 2, 0, 1, bA, bB, 1, 3);
    PHASE(it4 + 3, 1, 0, bB, bA, 2, 0);
  }
#undef PHASE
#undef PACK
#undef LOADB
#undef DMA

  // LN stats: reduce over lanes sharing a px-row-pair, then across waves.
#pragma unroll
  for (int off = 8; off < 64; off <<= 1) {
    sum0 += __shfl_xor(sum0, off, 64);  sq0 += __shfl_xor(sq0, off, 64);
    sum1 += __shfl_xor(sum1, off, 64);  sq1 += __shfl_xor(sq1, off, 64);
  }
  if (lane < 8) part4[wave][lane] = make_float4(sum0, sq0, sum1, sq1);
  __syncthreads();

  if (tid < 16) {
    int l = tid >> 1, odd = tid & 1;
    float s = 0.f, q = 0.f;
#pragma unroll
    for (int w = 0; w < 4; ++w) {
      float4 p = part4[w][l];
      s += odd ? p.z : p.x;
      q += odd ? p.w : p.y;
    }
    float mu  = s * (1.f / 768.f);
    float var = q * (1.f / 768.f) - mu * mu;
    smu[tid] = mu;
    srs[tid] = rsqrtf(var + 1e-5f);
  }
  __syncthreads();

  // Epilogue: LN folded via colsum trick; lane's 4 acc regs = 4 consecutive px.
  float4 mu4 = *(const float4*)&smu[lq * 4];
  float4 rs4 = *(const float4*)&srs[lq * 4];
  float* ob = out + (size_t)b * 3145728u + (size_t)dz * 1024u
                  + (size_t)hy * 32u + wh * 16 + lq * 4;
#pragma unroll
  for (int j = 0; j < 3; ++j) {
    int n = (wave * 3 + j) * 16 + lrow;
    float cs = colsum[n], bi = bias[n];
    float4 vv;
    vv.x = rs4.x * (acc[j][0] - mu4.x * cs) + bi;
    vv.y = rs4.y * (acc[j][1] - mu4.y * cs) + bi;
    vv.z = rs4.z * (acc[j][2] - mu4.z * cs) + bi;
    vv.w = rs4.w * (acc[j][3] - mu4.w * cs) + bi;
    *(float4*)(ob + (size_t)n * 16384u) = vv;
  }
}

extern "C" void kernel_launch(void* const* d_in, const int* in_sizes, int n_in,
                              void* d_out, int out_size, void* d_ws, size_t ws_size,
                              hipStream_t stream) {
  const float* x     = (const float*)d_in[0];
  const float* gamma = (const float*)d_in[1];
  const float* beta  = (const float*)d_in[2];
  const float* w_red = (const float*)d_in[3];
  float* out = (float*)d_out;

  unsigned short* w_frag = (unsigned short*)d_ws;          // 192*768*2 = 294912 B
  float* colsum = (float*)((char*)d_ws + 294912);          // 192 f32
  float* bias   = colsum + 192;                            // 192 f32

  prep_kernel<<<dim3(192), dim3(256), 0, stream>>>(w_red, gamma, beta, w_frag, colsum, bias);
  pm_kernel<<<dim3(2048), dim3(256), 0, stream>>>(x, w_frag, colsum, bias, out);
}

// Round 9
// 192.867 us; speedup vs baseline: 1.7089x; 1.7089x over previous
//
#include <hip/hip_runtime.h>

typedef __attribute__((ext_vector_type(8))) short short8;
typedef __attribute__((ext_vector_type(4))) float float4v;

__device__ __forceinline__ unsigned short f2bf(float f) {
  unsigned int u = __float_as_uint(f);
  u += 0x7fffu + ((u >> 16) & 1u);   // round-to-nearest-even
  return (unsigned short)(u >> 16);
}
__device__ __forceinline__ float bf2f(unsigned short h) {
  return __uint_as_float(((unsigned int)h) << 16);
}
__device__ __forceinline__ unsigned int pack2bf(float a, float b) {
  return (unsigned int)f2bf(a) | ((unsigned int)f2bf(b) << 16);
}

// ---- prep: w' = gamma*w -> bf16 in MFMA FRAGMENT ORDER + colsum + bias ------
// w_frag[((ntile*24 + kc)*64 + lq*16 + lrow)*8 + e]; n = ntile*16+lrow,
// k' = kc*32 + lq*8 + e; k_orig = (k'&7)*96 + (k'>>3).
__global__ __launch_bounds__(256)
void prep_kernel(const float* __restrict__ w_red, const float* __restrict__ gamma,
                 const float* __restrict__ beta, unsigned short* __restrict__ w_frag,
                 float* __restrict__ colsum, float* __restrict__ bias) {
  const int n = blockIdx.x;       // 0..191
  const int t = threadIdx.x;      // 0..255
  const int ntile = n >> 4, lrow = n & 15;
  float cs = 0.f, bs = 0.f;
#pragma unroll
  for (int j = 0; j < 3; ++j) {
    int kp = j * 256 + t;                       // k' 0..767
    int ko = (kp & 7) * 96 + (kp >> 3);         // original k
    float w = w_red[(size_t)ko * 192 + n];
    unsigned short v = f2bf(gamma[ko] * w);
    int kc = kp >> 5, r = kp & 31, lq = r >> 3, e = r & 7;
    w_frag[(size_t)((ntile * 24 + kc) * 64 + lq * 16 + lrow) * 8 + e] = v;
    cs += bf2f(v);
    bs += beta[ko] * w;
  }
#pragma unroll
  for (int off = 1; off < 64; off <<= 1) {
    cs += __shfl_xor(cs, off, 64);
    bs += __shfl_xor(bs, off, 64);
  }
  __shared__ float red[2][4];
  const int wave = t >> 6;
  if ((t & 63) == 0) { red[0][wave] = cs; red[1][wave] = bs; }
  __syncthreads();
  if (t == 0) {
    colsum[n] = red[0][0] + red[0][1] + red[0][2] + red[0][3];
    bias[n]   = red[1][0] + red[1][1] + red[1][2] + red[1][3];
  }
}

// ---- main: fused pipeline v3 — identical schedule to v2, but (256,4): ------
// VGPR cap 128 (v2's (256,6) cap 85 caused a spill cascade: VGPR=40,
// 500 MB scratch traffic). 4 blocks/CU x 21.5 KB LDS = 86 KB, ~50% occ.
// Per phase it: barrier | LOADB(it+1) | DMA(it+3) | vmcnt(8) | PACK(it+1)
// | 6 MFMA(it). Steady queue after vmcnt: [D(it+2), B(it+1)x6, D(it+3)] = 8.
__global__ __launch_bounds__(256, 4)
void pm_kernel(const float* __restrict__ x, const unsigned short* __restrict__ w_frag,
               const float* __restrict__ colsum, const float* __restrict__ bias,
               float* __restrict__ out) {
  __shared__ __align__(16) float F[4096];            // 4 slots x 1024 f32 (16 KB)
  __shared__ __align__(16) unsigned short Yb[2048];  // 2 x 16px x 64k bf16 (4 KB)
  __shared__ float4 part4[4][8];
  __shared__ float smu[16], srs[16];

  const int tid = threadIdx.x;
  const int bid = blockIdx.x;
  const int b  = bid >> 10;
  const int dz = (bid >> 6) & 15;
  const int hy = (bid >> 1) & 31;
  const int wh = bid & 1;

  const float* xb = x + (size_t)b * 12582912u + (size_t)dz * 8192u
                      + (size_t)hy * 128u + wh * 32;
  const int r0 = tid >> 3;
  const int c0 = r0 >> 2;          // 0..7; chunk channel c = c0 + 8*it
  const int di = (r0 >> 1) & 1;
  const int hi = r0 & 1;
  const int w0 = (tid & 7) << 2;
  const float* xp = xb + (size_t)c0 * 131072u + di * 4096 + hi * 64 + w0;

  const int lane = tid & 63;
  const int wave = tid >> 6;
  const int lrow = lane & 15;
  const int lq   = lane >> 4;

  // LDS addressing (bytes). A-tile rows are 128 B -> XOR-swizzle (G4).
  char* ybase = (char*)Yb;
  const int wx0 = (tid & 7) << 1;                  // px row pair written by thread
  const int k00 = c0 * 8 + di * 4 + hi * 2;        // chunk-local k (const!)
  const int b0off = (wx0 * 128 + k00 * 2) ^ ((wx0 & 7) << 4);
  const int b1off = ((wx0 + 1) * 128 + k00 * 2) ^ (((wx0 + 1) & 7) << 4);
  const int ra0 = (lrow * 128 + lq * 16) ^ ((lrow & 7) << 4);        // ks=0
  const int ra1 = (lrow * 128 + 64 + lq * 16) ^ ((lrow & 7) << 4);   // ks=1
  const int fth = wave * 256 + lane * 4;   // thread's float4 in an F slot
  const int fwv = wave * 256;              // wave-uniform DMA dest in an F slot

  // B fragment pointers (fragment-order w_frag -> contiguous 1KB/wave loads).
  const unsigned short* wb0 = w_frag + (size_t)(wave * 3 + 0) * 12288u + lane * 8;
  const unsigned short* wb1 = w_frag + (size_t)(wave * 3 + 1) * 12288u + lane * 8;
  const unsigned short* wb2 = w_frag + (size_t)(wave * 3 + 2) * 12288u + lane * 8;

  short8 bA[6], bB[6];
  float4v acc[3];
#pragma unroll
  for (int j = 0; j < 3; ++j)
#pragma unroll
    for (int r = 0; r < 4; ++r) acc[j][r] = 0.f;
  float sum0 = 0.f, sq0 = 0.f, sum1 = 0.f, sq1 = 0.f;

#define DMA(IT, SL)                                                            \
  __builtin_amdgcn_global_load_lds(                                            \
      (const __attribute__((address_space(1))) unsigned int*)(xp + (size_t)(IT) * 1048576u), \
      (__attribute__((address_space(3))) unsigned int*)&F[(SL) * 1024 + fwv], 16, 0, 0)

#define LOADB(BN, ITB)                                                         \
  do {                                                                         \
    const unsigned short* kp0 = wb0 + (ITB) * 1024;                            \
    BN[0] = *(const short8*)(kp0);                                             \
    BN[1] = *(const short8*)(kp0 + 512);                                       \
    const unsigned short* kp1 = wb1 + (ITB) * 1024;                            \
    BN[2] = *(const short8*)(kp1);                                             \
    BN[3] = *(const short8*)(kp1 + 512);                                       \
    const unsigned short* kp2 = wb2 + (ITB) * 1024;                            \
    BN[4] = *(const short8*)(kp2);                                             \
    BN[5] = *(const short8*)(kp2 + 512);                                       \
  } while (0)

#define PACK(SLP, PN)                                                          \
  do {                                                                         \
    float4 vv = *(const float4*)&F[(SLP) * 1024 + fth];                        \
    *(unsigned int*)(ybase + (PN) * 2048 + b0off) = pack2bf(vv.x, vv.y);       \
    *(unsigned int*)(ybase + (PN) * 2048 + b1off) = pack2bf(vv.z, vv.w);       \
    sum0 += vv.x + vv.y;  sq0 += vv.x * vv.x + vv.y * vv.y;                    \
    sum1 += vv.z + vv.w;  sq1 += vv.z * vv.z + vv.w * vv.w;                    \
  } while (0)

#define PHASE(IT, PC, PN, BC, BN, SLI, SLP)                                    \
  do {                                                                         \
    asm volatile("s_waitcnt lgkmcnt(0)" ::: "memory");                         \
    __builtin_amdgcn_s_barrier();                                              \
    { int itb = (IT) + 1 <= 11 ? (IT) + 1 : 11; LOADB(BN, itb); }              \
    __builtin_amdgcn_sched_barrier(0);                                         \
    { int itn = (IT) + 3 <= 11 ? (IT) + 3 : 11; DMA(itn, SLI); }               \
    __builtin_amdgcn_sched_barrier(0);                                         \
    asm volatile("s_waitcnt vmcnt(8)" ::: "memory");                           \
    __builtin_amdgcn_sched_barrier(0);                                         \
    if ((IT) < 11) PACK(SLP, PN);                                              \
    { short8 a0 = *(const short8*)(ybase + (PC) * 2048 + ra0);                 \
      short8 a1 = *(const short8*)(ybase + (PC) * 2048 + ra1);                 \
      acc[0] = __builtin_amdgcn_mfma_f32_16x16x32_bf16(a0, BC[0], acc[0], 0, 0, 0); \
      acc[0] = __builtin_amdgcn_mfma_f32_16x16x32_bf16(a1, BC[1], acc[0], 0, 0, 0); \
      acc[1] = __builtin_amdgcn_mfma_f32_16x16x32_bf16(a0, BC[2], acc[1], 0, 0, 0); \
      acc[1] = __builtin_amdgcn_mfma_f32_16x16x32_bf16(a1, BC[3], acc[1], 0, 0, 0); \
      acc[2] = __builtin_amdgcn_mfma_f32_16x16x32_bf16(a0, BC[4], acc[2], 0, 0, 0); \
      acc[2] = __builtin_amdgcn_mfma_f32_16x16x32_bf16(a1, BC[5], acc[2], 0, 0, 0); } \
  } while (0)

  // Prologue. Issue order D0,D1,B0x6,D2 -> queue 9; vmcnt(8) retires D0 only.
  // Entering phase 0: [D1, B0x6, D2] = 8 outstanding (the loop invariant).
  DMA(0, 0);
  __builtin_amdgcn_sched_barrier(0);
  DMA(1, 1);
  __builtin_amdgcn_sched_barrier(0);
  LOADB(bA, 0);
  __builtin_amdgcn_sched_barrier(0);
  DMA(2, 2);
  __builtin_amdgcn_sched_barrier(0);
  asm volatile("s_waitcnt vmcnt(8)" ::: "memory");
  __builtin_amdgcn_sched_barrier(0);
  PACK(0, 0);   // chunk 0 -> Yb parity 0

  // 12 phases; pattern period 4 (slots mod 4, parity mod 2, bA/bB mod 2).
#pragma unroll
  for (int it4 = 0; it4 < 12; it4 += 4) {
    PHASE(it4 + 0, 0, 1, bA, bB, 3, 1);
    PHASE(it4 + 1, 1, 0, bB, bA, 0, 2);
    PHASE(it4 + 2, 0, 1, bA, bB, 1, 3);
    PHASE(it4 + 3, 1, 0, bB, bA, 2, 0);
  }
#undef PHASE
#undef PACK
#undef LOADB
#undef DMA

  // LN stats: reduce over lanes sharing a px-row-pair, then across waves.
#pragma unroll
  for (int off = 8; off < 64; off <<= 1) {
    sum0 += __shfl_xor(sum0, off, 64);  sq0 += __shfl_xor(sq0, off, 64);
    sum1 += __shfl_xor(sum1, off, 64);  sq1 += __shfl_xor(sq1, off, 64);
  }
  if (lane < 8) part4[wave][lane] = make_float4(sum0, sq0, sum1, sq1);
  __syncthreads();

  if (tid < 16) {
    int l = tid >> 1, odd = tid & 1;
    float s = 0.f, q = 0.f;
#pragma unroll
    for (int w = 0; w < 4; ++w) {
      float4 p = part4[w][l];
      s += odd ? p.z : p.x;
      q += odd ? p.w : p.y;
    }
    float mu  = s * (1.f / 768.f);
    float var = q * (1.f / 768.f) - mu * mu;
    smu[tid] = mu;
    srs[tid] = rsqrtf(var + 1e-5f);
  }
  __syncthreads();

  // Epilogue: LN folded via colsum trick; lane's 4 acc regs = 4 consecutive px.
  float4 mu4 = *(const float4*)&smu[lq * 4];
  float4 rs4 = *(const float4*)&srs[lq * 4];
  float* ob = out + (size_t)b * 3145728u + (size_t)dz * 1024u
                  + (size_t)hy * 32u + wh * 16 + lq * 4;
#pragma unroll
  for (int j = 0; j < 3; ++j) {
    int n = (wave * 3 + j) * 16 + lrow;
    float cs = colsum[n], bi = bias[n];
    float4 vv;
    vv.x = rs4.x * (acc[j][0] - mu4.x * cs) + bi;
    vv.y = rs4.y * (acc[j][1] - mu4.y * cs) + bi;
    vv.z = rs4.z * (acc[j][2] - mu4.z * cs) + bi;
    vv.w = rs4.w * (acc[j][3] - mu4.w * cs) + bi;
    *(float4*)(ob + (size_t)n * 16384u) = vv;
  }
}

extern "C" void kernel_launch(void* const* d_in, const int* in_sizes, int n_in,
                              void* d_out, int out_size, void* d_ws, size_t ws_size,
                              hipStream_t stream) {
  const float* x     = (const float*)d_in[0];
  const float* gamma = (const float*)d_in[1];
  const float* beta  = (const float*)d_in[2];
  const float* w_red = (const float*)d_in[3];
  float* out = (float*)d_out;

  unsigned short* w_frag = (unsigned short*)d_ws;          // 192*768*2 = 294912 B
  float* colsum = (float*)((char*)d_ws + 294912);          // 192 f32
  float* bias   = colsum + 192;                            // 192 f32

  prep_kernel<<<dim3(192), dim3(256), 0, stream>>>(w_red, gamma, beta, w_frag, colsum, bias);
  pm_kernel<<<dim3(2048), dim3(256), 0, stream>>>(x, w_frag, colsum, bias, out);
}

// Round 10
// 185.256 us; speedup vs baseline: 1.7791x; 1.0411x over previous
//
#include <hip/hip_runtime.h>

typedef __attribute__((ext_vector_type(8))) short short8;
typedef __attribute__((ext_vector_type(4))) float float4v;

__device__ __forceinline__ unsigned short f2bf(float f) {
  unsigned int u = __float_as_uint(f);
  u += 0x7fffu + ((u >> 16) & 1u);   // round-to-nearest-even
  return (unsigned short)(u >> 16);
}
__device__ __forceinline__ float bf2f(unsigned short h) {
  return __uint_as_float(((unsigned int)h) << 16);
}
__device__ __forceinline__ unsigned int pack2bf(float a, float b) {
  return (unsigned int)f2bf(a) | ((unsigned int)f2bf(b) << 16);
}

// ---- prep: w' = gamma*w -> bf16 in MFMA FRAGMENT ORDER + colsum + bias ------
// w_frag[((ntile*24 + kc)*64 + lq*16 + lrow)*8 + e]; n = ntile*16+lrow,
// k' = kc*32 + lq*8 + e; k_orig = (k'&7)*96 + (k'>>3).
__global__ __launch_bounds__(256)
void prep_kernel(const float* __restrict__ w_red, const float* __restrict__ gamma,
                 const float* __restrict__ beta, unsigned short* __restrict__ w_frag,
                 float* __restrict__ colsum, float* __restrict__ bias) {
  const int n = blockIdx.x;       // 0..191
  const int t = threadIdx.x;      // 0..255
  const int ntile = n >> 4, lrow = n & 15;
  float cs = 0.f, bs = 0.f;
#pragma unroll
  for (int j = 0; j < 3; ++j) {
    int kp = j * 256 + t;                       // k' 0..767
    int ko = (kp & 7) * 96 + (kp >> 3);         // original k
    float w = w_red[(size_t)ko * 192 + n];
    unsigned short v = f2bf(gamma[ko] * w);
    int kc = kp >> 5, r = kp & 31, lq = r >> 3, e = r & 7;
    w_frag[(size_t)((ntile * 24 + kc) * 64 + lq * 16 + lrow) * 8 + e] = v;
    cs += bf2f(v);
    bs += beta[ko] * w;
  }
#pragma unroll
  for (int off = 1; off < 64; off <<= 1) {
    cs += __shfl_xor(cs, off, 64);
    bs += __shfl_xor(bs, off, 64);
  }
  __shared__ float red[2][4];
  const int wave = t >> 6;
  if ((t & 63) == 0) { red[0][wave] = cs; red[1][wave] = bs; }
  __syncthreads();
  if (t == 0) {
    colsum[n] = red[0][0] + red[0][1] + red[0][2] + red[0][3];
    bias[n]   = red[1][0] + red[1][1] + red[1][2] + red[1][3];
  }
}

// ---- main: fused pipeline v4 — M=32 px/block (halves phase count/CU and ----
// per-output B traffic vs v3). Grid 1024. Per phase it: barrier | LOADB(it+1)
// | DMA(it+3)x2 | vmcnt(10) | PACK(it+1) | 12 MFMA(it).
// Steady queue after vmcnt: [D(it+2)x2, B(it+1)x6, D(it+3)x2] = 10.
__global__ __launch_bounds__(256, 3)
void pm_kernel(const float* __restrict__ x, const unsigned short* __restrict__ w_frag,
               const float* __restrict__ colsum, const float* __restrict__ bias,
               float* __restrict__ out) {
  __shared__ __align__(16) float F[8192];            // 4 slots x 2048 f32 (32 KB)
  __shared__ __align__(16) unsigned short Yb[4096];  // 2 x 32px x 64k bf16 (8 KB)
  __shared__ float4 part4[4][16];
  __shared__ float smu[32], srs[32];

  const int tid = threadIdx.x;
  const int bid = blockIdx.x;
  const int b  = bid >> 9;
  const int dz = (bid >> 5) & 15;
  const int hy = bid & 31;

  const float* xb = x + (size_t)b * 12582912u + (size_t)dz * 8192u
                      + (size_t)hy * 128u;

  const int lane = tid & 63;
  const int wave = tid >> 6;
  const int lrow = lane & 15;
  const int lq   = lane >> 4;

  // DMA source: DMA d of wave w covers c0 = 2w+d; lane -> (di,hi,w0):
  // di=(lane>>5)&1, hi=(lane>>4)&1, w-float = 4*(lane&15). 2x512B contiguous.
  const int di = (lane >> 5) & 1;
  const int hi = (lane >> 4) & 1;
  const float* xp0 = xb + (size_t)(2 * wave) * 131072u + di * 4096 + hi * 64
                        + ((lane & 15) << 2);
  const float* xp1 = xp0 + 131072u;

  // LDS addressing (bytes). Yb parity region = 32px x 128B rows, XOR swizzle.
  char* ybase = (char*)Yb;
  const int wx0 = (lane & 15) << 1;                // px pair this thread packs
  const int k0d0 = wave * 16 + di * 4 + hi * 2;    // chunk-local k, d=0
  const int k0d1 = k0d0 + 8;                       // d=1
  const int b00 = (wx0 * 128 + k0d0 * 2) ^ ((wx0 & 7) << 4);
  const int b01 = ((wx0 + 1) * 128 + k0d0 * 2) ^ (((wx0 + 1) & 7) << 4);
  const int b10 = (wx0 * 128 + k0d1 * 2) ^ ((wx0 & 7) << 4);
  const int b11 = ((wx0 + 1) * 128 + k0d1 * 2) ^ (((wx0 + 1) & 7) << 4);
  // A-fragment reads: row = mt*16+lrow, ks in {0,1}.
  const int ra00 = (lrow * 128 + lq * 16) ^ ((lrow & 7) << 4);
  const int ra01 = (lrow * 128 + 64 + lq * 16) ^ ((lrow & 7) << 4);
  const int ra10 = ((16 + lrow) * 128 + lq * 16) ^ ((lrow & 7) << 4);
  const int ra11 = ((16 + lrow) * 128 + 64 + lq * 16) ^ ((lrow & 7) << 4);
  const int fth = wave * 512 + lane * 4;   // thread's d=0 float4 in an F slot
  const int fwv = wave * 512;              // wave-uniform DMA dest base

  // B fragment pointers (fragment-order w_frag -> contiguous 1KB/wave loads).
  const unsigned short* wb0 = w_frag + (size_t)(wave * 3 + 0) * 12288u + lane * 8;
  const unsigned short* wb1 = w_frag + (size_t)(wave * 3 + 1) * 12288u + lane * 8;
  const unsigned short* wb2 = w_frag + (size_t)(wave * 3 + 2) * 12288u + lane * 8;

  short8 bA[6], bB[6];
  float4v acc[2][3];
#pragma unroll
  for (int mt = 0; mt < 2; ++mt)
#pragma unroll
    for (int j = 0; j < 3; ++j)
#pragma unroll
      for (int r = 0; r < 4; ++r) acc[mt][j][r] = 0.f;
  float sum0 = 0.f, sq0 = 0.f, sum1 = 0.f, sq1 = 0.f;

#define DMA2(IT, SL)                                                           \
  do {                                                                         \
    __builtin_amdgcn_global_load_lds(                                          \
        (const __attribute__((address_space(1))) unsigned int*)(xp0 + (size_t)(IT) * 1048576u), \
        (__attribute__((address_space(3))) unsigned int*)&F[(SL) * 2048 + fwv], 16, 0, 0); \
    __builtin_amdgcn_global_load_lds(                                          \
        (const __attribute__((address_space(1))) unsigned int*)(xp1 + (size_t)(IT) * 1048576u), \
        (__attribute__((address_space(3))) unsigned int*)&F[(SL) * 2048 + fwv + 256], 16, 0, 0); \
  } while (0)

#define LOADB(BN, ITB)                                                         \
  do {                                                                         \
    const unsigned short* kp0 = wb0 + (ITB) * 1024;                            \
    BN[0] = *(const short8*)(kp0);                                             \
    BN[1] = *(const short8*)(kp0 + 512);                                       \
    const unsigned short* kp1 = wb1 + (ITB) * 1024;                            \
    BN[2] = *(const short8*)(kp1);                                             \
    BN[3] = *(const short8*)(kp1 + 512);                                       \
    const unsigned short* kp2 = wb2 + (ITB) * 1024;                            \
    BN[4] = *(const short8*)(kp2);                                             \
    BN[5] = *(const short8*)(kp2 + 512);                                       \
  } while (0)

#define PACK(SLP, PN)                                                          \
  do {                                                                         \
    float4 v0 = *(const float4*)&F[(SLP) * 2048 + fth];                        \
    float4 v1 = *(const float4*)&F[(SLP) * 2048 + fth + 256];                  \
    *(unsigned int*)(ybase + (PN) * 4096 + b00) = pack2bf(v0.x, v0.y);         \
    *(unsigned int*)(ybase + (PN) * 4096 + b01) = pack2bf(v0.z, v0.w);         \
    *(unsigned int*)(ybase + (PN) * 4096 + b10) = pack2bf(v1.x, v1.y);         \
    *(unsigned int*)(ybase + (PN) * 4096 + b11) = pack2bf(v1.z, v1.w);         \
    sum0 += v0.x + v0.y + v1.x + v1.y;                                         \
    sq0  += v0.x * v0.x + v0.y * v0.y + v1.x * v1.x + v1.y * v1.y;             \
    sum1 += v0.z + v0.w + v1.z + v1.w;                                         \
    sq1  += v0.z * v0.z + v0.w * v0.w + v1.z * v1.z + v1.w * v1.w;             \
  } while (0)

#define PHASE(IT, PC, PN, BC, BN, SLI, SLP)                                    \
  do {                                                                         \
    asm volatile("s_waitcnt lgkmcnt(0)" ::: "memory");                         \
    __builtin_amdgcn_s_barrier();                                              \
    { int itb = (IT) + 1 <= 11 ? (IT) + 1 : 11; LOADB(BN, itb); }              \
    __builtin_amdgcn_sched_barrier(0);                                         \
    { int itn = (IT) + 3 <= 11 ? (IT) + 3 : 11; DMA2(itn, SLI); }              \
    __builtin_amdgcn_sched_barrier(0);                                         \
    asm volatile("s_waitcnt vmcnt(10)" ::: "memory");                          \
    __builtin_amdgcn_sched_barrier(0);                                         \
    if ((IT) < 11) PACK(SLP, PN);                                              \
    { short8 a00 = *(const short8*)(ybase + (PC) * 4096 + ra00);               \
      short8 a01 = *(const short8*)(ybase + (PC) * 4096 + ra01);               \
      short8 a10 = *(const short8*)(ybase + (PC) * 4096 + ra10);               \
      short8 a11 = *(const short8*)(ybase + (PC) * 4096 + ra11);               \
      acc[0][0] = __builtin_amdgcn_mfma_f32_16x16x32_bf16(a00, BC[0], acc[0][0], 0, 0, 0); \
      acc[0][0] = __builtin_amdgcn_mfma_f32_16x16x32_bf16(a01, BC[1], acc[0][0], 0, 0, 0); \
      acc[1][0] = __builtin_amdgcn_mfma_f32_16x16x32_bf16(a10, BC[0], acc[1][0], 0, 0, 0); \
      acc[1][0] = __builtin_amdgcn_mfma_f32_16x16x32_bf16(a11, BC[1], acc[1][0], 0, 0, 0); \
      acc[0][1] = __builtin_amdgcn_mfma_f32_16x16x32_bf16(a00, BC[2], acc[0][1], 0, 0, 0); \
      acc[0][1] = __builtin_amdgcn_mfma_f32_16x16x32_bf16(a01, BC[3], acc[0][1], 0, 0, 0); \
      acc[1][1] = __builtin_amdgcn_mfma_f32_16x16x32_bf16(a10, BC[2], acc[1][1], 0, 0, 0); \
      acc[1][1] = __builtin_amdgcn_mfma_f32_16x16x32_bf16(a11, BC[3], acc[1][1], 0, 0, 0); \
      acc[0][2] = __builtin_amdgcn_mfma_f32_16x16x32_bf16(a00, BC[4], acc[0][2], 0, 0, 0); \
      acc[0][2] = __builtin_amdgcn_mfma_f32_16x16x32_bf16(a01, BC[5], acc[0][2], 0, 0, 0); \
      acc[1][2] = __builtin_amdgcn_mfma_f32_16x16x32_bf16(a10, BC[4], acc[1][2], 0, 0, 0); \
      acc[1][2] = __builtin_amdgcn_mfma_f32_16x16x32_bf16(a11, BC[5], acc[1][2], 0, 0, 0); } \
  } while (0)

  // Prologue. Issue D0x2,D1x2,B0x6,D2x2 -> 12 outstanding; vmcnt(10) retires
  // D0 pair. Entering phase 0: [D1x2, B0x6, D2x2] = 10 (the loop invariant).
  DMA2(0, 0);
  __builtin_amdgcn_sched_barrier(0);
  DMA2(1, 1);
  __builtin_amdgcn_sched_barrier(0);
  LOADB(bA, 0);
  __builtin_amdgcn_sched_barrier(0);
  DMA2(2, 2);
  __builtin_amdgcn_sched_barrier(0);
  asm volatile("s_waitcnt vmcnt(10)" ::: "memory");
  __builtin_amdgcn_sched_barrier(0);
  PACK(0, 0);   // chunk 0 -> Yb parity 0

  // 12 phases; pattern period 4 (slots mod 4, parity mod 2, bA/bB mod 2).
#pragma unroll
  for (int it4 = 0; it4 < 12; it4 += 4) {
    PHASE(it4 + 0, 0, 1, bA, bB, 3, 1);
    PHASE(it4 + 1, 1, 0, bB, bA, 0, 2);
    PHASE(it4 + 2, 0, 1, bA, bB, 1, 3);
    PHASE(it4 + 3, 1, 0, bB, bA, 2, 0);
  }
#undef PHASE
#undef PACK
#undef LOADB
#undef DMA2

  // LN stats: lanes sharing (lane&15) hold the same px pair -> reduce over
  // lane>>4 groups, then across waves.
#pragma unroll
  for (int off = 16; off < 64; off <<= 1) {
    sum0 += __shfl_xor(sum0, off, 64);  sq0 += __shfl_xor(sq0, off, 64);
    sum1 += __shfl_xor(sum1, off, 64);  sq1 += __shfl_xor(sq1, off, 64);
  }
  if (lane < 16) part4[wave][lane] = make_float4(sum0, sq0, sum1, sq1);
  __syncthreads();

  if (tid < 32) {
    int sp = tid >> 1, odd = tid & 1;
    float s = 0.f, q = 0.f;
#pragma unroll
    for (int w = 0; w < 4; ++w) {
      float4 p = part4[w][sp];
      s += odd ? p.z : p.x;
      q += odd ? p.w : p.y;
    }
    float mu  = s * (1.f / 768.f);
    float var = q * (1.f / 768.f) - mu * mu;
    smu[tid] = mu;
    srs[tid] = rsqrtf(var + 1e-5f);
  }
  __syncthreads();

  // Epilogue: LN folded via colsum trick; acc[mt][j] row = px mt*16+lq*4+r.
  float4 mu4a = *(const float4*)&smu[lq * 4];
  float4 rs4a = *(const float4*)&srs[lq * 4];
  float4 mu4b = *(const float4*)&smu[16 + lq * 4];
  float4 rs4b = *(const float4*)&srs[16 + lq * 4];
  float* ob = out + (size_t)b * 3145728u + (size_t)dz * 1024u + (size_t)hy * 32u;
#pragma unroll
  for (int j = 0; j < 3; ++j) {
    int n = (wave * 3 + j) * 16 + lrow;
    float cs = colsum[n], bi = bias[n];
    float4 vv;
    vv.x = rs4a.x * (acc[0][j][0] - mu4a.x * cs) + bi;
    vv.y = rs4a.y * (acc[0][j][1] - mu4a.y * cs) + bi;
    vv.z = rs4a.z * (acc[0][j][2] - mu4a.z * cs) + bi;
    vv.w = rs4a.w * (acc[0][j][3] - mu4a.w * cs) + bi;
    *(float4*)(ob + (size_t)n * 16384u + lq * 4) = vv;
    vv.x = rs4b.x * (acc[1][j][0] - mu4b.x * cs) + bi;
    vv.y = rs4b.y * (acc[1][j][1] - mu4b.y * cs) + bi;
    vv.z = rs4b.z * (acc[1][j][2] - mu4b.z * cs) + bi;
    vv.w = rs4b.w * (acc[1][j][3] - mu4b.w * cs) + bi;
    *(float4*)(ob + (size_t)n * 16384u + 16 + lq * 4) = vv;
  }
}

extern "C" void kernel_launch(void* const* d_in, const int* in_sizes, int n_in,
                              void* d_out, int out_size, void* d_ws, size_t ws_size,
                              hipStream_t stream) {
  const float* x     = (const float*)d_in[0];
  const float* gamma = (const float*)d_in[1];
  const float* beta  = (const float*)d_in[2];
  const float* w_red = (const float*)d_in[3];
  float* out = (float*)d_out;

  unsigned short* w_frag = (unsigned short*)d_ws;          // 192*768*2 = 294912 B
  float* colsum = (float*)((char*)d_ws + 294912);          // 192 f32
  float* bias   = colsum + 192;                            // 192 f32

  prep_kernel<<<dim3(192), dim3(256), 0, stream>>>(w_red, gamma, beta, w_frag, colsum, bias);
  pm_kernel<<<dim3(1024), dim3(256), 0, stream>>>(x, w_frag, colsum, bias, out);
}